// Round 3
// baseline (1574.056 us; speedup 1.0000x reference)
//
#include <hip/hip_runtime.h>

#define USER_NUM   100000
#define ITEM_NUM   50000
#define N_NODES    (USER_NUM + ITEM_NUM)
#define NNZ        4800000
#define EMB        64
#define N_LAYERS   3
#define EPS_F      0.2f
#define NORM_EPS_F 1e-12f

#define N_BUCKETS  ((N_NODES + 63) / 64)   // 2344 buckets of 64 rows

#define SCAN_TPB    1024
#define SCAN_BLOCKS ((N_NODES + SCAN_TPB - 1) / SCAN_TPB)   // 147
static_assert(SCAN_BLOCKS <= 256, "scan2 single block assumption");

// ---------------- CSR build ----------------

__global__ void zero_ints(int* __restrict__ p, int n) {
    int i = blockIdx.x * blockDim.x + threadIdx.x;
    int stride = gridDim.x * blockDim.x;
    for (; i < n; i += stride) p[i] = 0;
}

__global__ void hist_kernel(const int* __restrict__ rows, int* __restrict__ counts) {
    int i = blockIdx.x * blockDim.x + threadIdx.x;
    int stride = gridDim.x * blockDim.x;
    for (; i < NNZ; i += stride) atomicAdd(&counts[rows[i]], 1);
}

__global__ __launch_bounds__(SCAN_TPB) void scan1_kernel(const int* __restrict__ counts,
                                                         int* __restrict__ row_ptr,
                                                         int* __restrict__ bsums) {
    __shared__ int s[SCAN_TPB];
    int tid = threadIdx.x;
    int i = blockIdx.x * SCAN_TPB + tid;
    int c = (i < N_NODES) ? counts[i] : 0;
    s[tid] = c;
    __syncthreads();
    for (int off = 1; off < SCAN_TPB; off <<= 1) {
        int t = (tid >= off) ? s[tid - off] : 0;
        __syncthreads();
        s[tid] += t;
        __syncthreads();
    }
    if (i < N_NODES) row_ptr[i] = s[tid] - c;   // exclusive
    if (tid == SCAN_TPB - 1) bsums[blockIdx.x] = s[tid];
}

__global__ __launch_bounds__(256) void scan2_kernel(int* __restrict__ bsums, int n) {
    __shared__ int s[256];
    int tid = threadIdx.x;
    int c = (tid < n) ? bsums[tid] : 0;
    s[tid] = c;
    __syncthreads();
    for (int off = 1; off < 256; off <<= 1) {
        int t = (tid >= off) ? s[tid - off] : 0;
        __syncthreads();
        s[tid] += t;
        __syncthreads();
    }
    if (tid < n) bsums[tid] = s[tid] - c;       // exclusive
}

__global__ __launch_bounds__(SCAN_TPB) void scan3_kernel(int* __restrict__ row_ptr,
                                                         const int* __restrict__ bsums) {
    int i = blockIdx.x * SCAN_TPB + threadIdx.x;
    if (i < N_NODES) row_ptr[i] += bsums[blockIdx.x];
    else if (i == N_NODES) row_ptr[i] = NNZ;
}

// bucket cursors start at each bucket's CSR segment base
__global__ void init_bcursor(const int* __restrict__ row_ptr, int* __restrict__ bcursor) {
    int b = blockIdx.x * blockDim.x + threadIdx.x;
    if (b < N_BUCKETS) bcursor[b] = row_ptr[b * 64];
}

// Phase A: bin edges into 64-row buckets. Writes advance sequentially per
// bucket front -> line-dense. Pack (row&63)<<18 | col (col < 2^18) + val.
__global__ void binA_kernel(const int* __restrict__ rows, const int* __restrict__ cols,
                            const float* __restrict__ vals,
                            int* __restrict__ bcursor, int2* __restrict__ staging) {
    int i = blockIdx.x * blockDim.x + threadIdx.x;
    int stride = gridDim.x * blockDim.x;
    for (; i < NNZ; i += stride) {
        int r = rows[i];
        int pos = atomicAdd(&bcursor[r >> 6], 1);
        staging[pos] = make_int2(cols[i] | ((r & 63) << 18), __float_as_int(vals[i]));
    }
}

// Phase B: per-bucket fine scatter into the bucket's contiguous CSR segment
// (~16KB) using LDS row cursors -> line-dense writes.
__global__ __launch_bounds__(256) void binB_kernel(const int* __restrict__ row_ptr,
                                                   const int2* __restrict__ staging,
                                                   int2* __restrict__ edges) {
    __shared__ int cursor[64];
    int b = blockIdx.x;
    int rbase = b * 64;
    int segbase = row_ptr[rbase];
    int segend = row_ptr[min(rbase + 64, N_NODES)];
    int t = threadIdx.x;
    if (t < 64) {
        int row = rbase + t;
        cursor[t] = ((row < N_NODES) ? row_ptr[row] : segend) - segbase;
    }
    __syncthreads();
    for (int i = segbase + t; i < segend; i += 256) {
        int2 e = staging[i];
        int rl = ((unsigned)e.x) >> 18;
        int col = e.x & ((1 << 18) - 1);
        int pos = atomicAdd(&cursor[rl], 1);
        edges[segbase + pos] = make_int2(col, e.y);
    }
}

// ---------------- SpMM + perturbation + mean ----------------
// One wave per row; 4 groups of 16 lanes, each group handles one edge per
// gather with float4 (16 lanes x 16B = 256B row vector). Cross-group
// reduction via shfl_xor(16,32).
// mode 0: out = v, x_out = v ; mode 1: out += v, x_out = v ; mode 2: out = (out+v)/3
__global__ __launch_bounds__(256) void spmm_layer_kernel(const float* __restrict__ xu,
                                                         const float* __restrict__ xi,
                                                         float* __restrict__ x_out,
                                                         const int* __restrict__ row_ptr,
                                                         const int2* __restrict__ edges,
                                                         const float* __restrict__ noise_k,
                                                         float* __restrict__ out, int mode) {
    int lane = threadIdx.x & 63;
    int row = blockIdx.x * 4 + (threadIdx.x >> 6);
    if (row >= N_NODES) return;
    int g = lane >> 4;        // edge slot within chunk
    int sub = lane & 15;      // float4 index within the 64-dim row

    int beg = row_ptr[row];
    int end = row_ptr[row + 1];
    int lim = end - 1;

    float4 acc = make_float4(0.f, 0.f, 0.f, 0.f);

    for (int base = beg; base < end; base += 8) {
        int i0 = base + g;
        int i1 = base + 4 + g;
        int2 e0 = edges[min(i0, lim)];
        int2 e1 = edges[min(i1, lim)];
        const float4* q0 = (e0.x < USER_NUM) ? (const float4*)(xu + (long)e0.x * EMB)
                                             : (const float4*)(xi + (long)(e0.x - USER_NUM) * EMB);
        const float4* q1 = (e1.x < USER_NUM) ? (const float4*)(xu + (long)e1.x * EMB)
                                             : (const float4*)(xi + (long)(e1.x - USER_NUM) * EMB);
        float4 x0 = q0[sub];
        float4 x1 = q1[sub];
        float w0 = (i0 < end) ? __int_as_float(e0.y) : 0.f;
        float w1 = (i1 < end) ? __int_as_float(e1.y) : 0.f;
        acc.x += w0 * x0.x; acc.y += w0 * x0.y; acc.z += w0 * x0.z; acc.w += w0 * x0.w;
        acc.x += w1 * x1.x; acc.y += w1 * x1.y; acc.z += w1 * x1.z; acc.w += w1 * x1.w;
    }

    // fold the 4 edge-groups: lanes with equal `sub` hold partials of same dims
    acc.x += __shfl_xor(acc.x, 16, 64); acc.x += __shfl_xor(acc.x, 32, 64);
    acc.y += __shfl_xor(acc.y, 16, 64); acc.y += __shfl_xor(acc.y, 32, 64);
    acc.z += __shfl_xor(acc.z, 16, 64); acc.z += __shfl_xor(acc.z, 32, 64);
    acc.w += __shfl_xor(acc.w, 16, 64); acc.w += __shfl_xor(acc.w, 32, 64);

    // perturbation: v = acc + sign(acc) * (r/max(||r||,eps)) * EPS
    const float4* nz = (const float4*)(noise_k + (long)row * EMB);
    float4 r4 = nz[sub];                       // all 4 groups load identical data
    float ss = r4.x * r4.x + r4.y * r4.y + r4.z * r4.z + r4.w * r4.w;
    ss += __shfl_xor(ss, 1, 64);
    ss += __shfl_xor(ss, 2, 64);
    ss += __shfl_xor(ss, 4, 64);
    ss += __shfl_xor(ss, 8, 64);               // per-16-lane group = full row norm^2
    float s = EPS_F / fmaxf(sqrtf(ss), NORM_EPS_F);

    float4 v;
    v.x = acc.x + ((acc.x > 0.f) ? 1.f : ((acc.x < 0.f) ? -1.f : 0.f)) * r4.x * s;
    v.y = acc.y + ((acc.y > 0.f) ? 1.f : ((acc.y < 0.f) ? -1.f : 0.f)) * r4.y * s;
    v.z = acc.z + ((acc.z > 0.f) ? 1.f : ((acc.z < 0.f) ? -1.f : 0.f)) * r4.z * s;
    v.w = acc.w + ((acc.w > 0.f) ? 1.f : ((acc.w < 0.f) ? -1.f : 0.f)) * r4.w * s;

    if (g == 0) {
        float4* po = (float4*)(out + (long)row * EMB);
        if (mode == 0) {
            po[sub] = v;
            ((float4*)(x_out + (long)row * EMB))[sub] = v;
        } else if (mode == 1) {
            float4 o = po[sub];
            o.x += v.x; o.y += v.y; o.z += v.z; o.w += v.w;
            po[sub] = o;
            ((float4*)(x_out + (long)row * EMB))[sub] = v;
        } else {
            float4 o = po[sub];
            o.x = (o.x + v.x) * (1.f / 3.f);
            o.y = (o.y + v.y) * (1.f / 3.f);
            o.z = (o.z + v.z) * (1.f / 3.f);
            o.w = (o.w + v.w) * (1.f / 3.f);
            po[sub] = o;
        }
    }
}

// ---------------- launch ----------------

extern "C" void kernel_launch(void* const* d_in, const int* in_sizes, int n_in,
                              void* d_out, int out_size, void* d_ws, size_t ws_size,
                              hipStream_t stream) {
    const float* user_emb = (const float*)d_in[0];
    const float* item_emb = (const float*)d_in[1];
    const int*   adj_rows = (const int*)d_in[2];
    const int*   adj_cols = (const int*)d_in[3];
    const float* adj_vals = (const float*)d_in[4];
    const float* noise    = (const float*)d_in[5];
    float* out = (float*)d_out;

    char* ws = (char*)d_ws;
    size_t off = 0;
    auto alloc = [&](size_t bytes) {
        char* p = ws + off;
        off += (bytes + 15) & ~size_t(15);
        return p;
    };
    int*   row_ptr = (int*)alloc((N_NODES + 1) * sizeof(int));
    int*   counts  = (int*)alloc(N_NODES * sizeof(int));
    int*   bsums   = (int*)alloc(256 * sizeof(int));
    int*   bcursor = (int*)alloc(N_BUCKETS * sizeof(int));
    int2*  edges   = (int2*)alloc((size_t)NNZ * sizeof(int2));
    float* ego_a   = (float*)alloc((size_t)N_NODES * EMB * sizeof(float));
    float* ego_b   = (float*)alloc((size_t)N_NODES * EMB * sizeof(float));
    // staging aliases ego_b: both are 38.4 MB and staging is dead before
    // layer-1 spmm (the first writer of ego_b) runs.
    int2* staging = (int2*)ego_b;

    // ---- CSR build ----
    zero_ints<<<587, 256, 0, stream>>>(counts, N_NODES);
    hist_kernel<<<4096, 256, 0, stream>>>(adj_rows, counts);
    scan1_kernel<<<SCAN_BLOCKS, SCAN_TPB, 0, stream>>>(counts, row_ptr, bsums);
    scan2_kernel<<<1, 256, 0, stream>>>(bsums, SCAN_BLOCKS);
    scan3_kernel<<<SCAN_BLOCKS, SCAN_TPB, 0, stream>>>(row_ptr, bsums);
    init_bcursor<<<(N_BUCKETS + 255) / 256, 256, 0, stream>>>(row_ptr, bcursor);
    binA_kernel<<<4096, 256, 0, stream>>>(adj_rows, adj_cols, adj_vals, bcursor, staging);
    binB_kernel<<<N_BUCKETS, 256, 0, stream>>>(row_ptr, staging, edges);

    // ---- 3 layers; layer 0 reads user_emb/item_emb directly (no concat) ----
    const int LGRID = (N_NODES + 3) / 4;
    const size_t NE = (size_t)N_NODES * EMB;
    spmm_layer_kernel<<<LGRID, 256, 0, stream>>>(user_emb, item_emb, ego_a,
                                                 row_ptr, edges, noise + 0 * NE, out, 0);
    spmm_layer_kernel<<<LGRID, 256, 0, stream>>>(ego_a, ego_a + (size_t)USER_NUM * EMB, ego_b,
                                                 row_ptr, edges, noise + 1 * NE, out, 1);
    spmm_layer_kernel<<<LGRID, 256, 0, stream>>>(ego_b, ego_b + (size_t)USER_NUM * EMB, nullptr,
                                                 row_ptr, edges, noise + 2 * NE, out, 2);
}

// Round 4
// 988.497 us; speedup vs baseline: 1.5924x; 1.5924x over previous
//
#include <hip/hip_runtime.h>

#define USER_NUM   100000
#define ITEM_NUM   50000
#define N_NODES    (USER_NUM + ITEM_NUM)
#define NNZ        4800000
#define EMB        64
#define EPS_F      0.2f
#define NORM_EPS_F 1e-12f

// coarse buckets of 1024 rows
#define RB_SHIFT   10
#define RB         1024
#define NB         ((N_NODES + RB - 1) / RB)     // 147
#define CAP        36864                          // per-bucket staging capacity (mean 32768, +22 sigma)
#define BINA_CHUNK 16384
#define BINA_GRID  ((NNZ + BINA_CHUNK - 1) / BINA_CHUNK)  // 293

__global__ void init_gcursor(int* __restrict__ g) {
    int b = blockIdx.x * blockDim.x + threadIdx.x;
    if (b < NB) g[b] = b * CAP;
}

// Phase A: block-private two-pass binning. Each block owns a contiguous chunk
// of the edge list; reserves ONE contiguous run per bucket via a single global
// atomic, then writes that run from this CU only -> line-dense writes.
__global__ __launch_bounds__(1024) void binA_kernel(const int* __restrict__ rows,
                                                    const int* __restrict__ cols,
                                                    const float* __restrict__ vals,
                                                    int* __restrict__ gcursor,
                                                    int2* __restrict__ staging) {
    __shared__ int hist[NB];
    __shared__ int cur[NB];
    int t = threadIdx.x;
    int cbeg = blockIdx.x * BINA_CHUNK;
    int cend = min(cbeg + BINA_CHUNK, NNZ);

    if (t < NB) hist[t] = 0;
    __syncthreads();
#pragma unroll 4
    for (int i = cbeg + t; i < cend; i += 1024)
        atomicAdd(&hist[rows[i] >> RB_SHIFT], 1);
    __syncthreads();
    if (t < NB) cur[t] = atomicAdd(&gcursor[t], hist[t]);   // reserve contiguous run
    __syncthreads();
#pragma unroll 4
    for (int i = cbeg + t; i < cend; i += 1024) {
        int r = rows[i];
        int pos = atomicAdd(&cur[r >> RB_SHIFT], 1);
        staging[pos] = make_int2(((r & (RB - 1)) << 18) | cols[i], __float_as_int(vals[i]));
    }
}

// exclusive scan of bucket counts -> bucket_base; sentinel row_ptr[N_NODES]
__global__ __launch_bounds__(256) void bscan_kernel(const int* __restrict__ gcursor,
                                                    int* __restrict__ bucket_base,
                                                    int* __restrict__ row_ptr) {
    __shared__ int s[256];
    int t = threadIdx.x;
    int c = (t < NB) ? (gcursor[t] - t * CAP) : 0;
    s[t] = c;
    __syncthreads();
    for (int off = 1; off < 256; off <<= 1) {
        int tv = (t >= off) ? s[t - off] : 0;
        __syncthreads();
        s[t] += tv;
        __syncthreads();
    }
    if (t < NB) bucket_base[t] = s[t] - c;
    if (t == 0) row_ptr[N_NODES] = NNZ;
}

// Phase B: one block per bucket. LDS hist over the bucket's 1024 rows, LDS
// scan -> row_ptr (no separate histogram/scan kernels needed), then scatter
// into the bucket's contiguous CSR segment (~260KB, single CU -> dense).
__global__ __launch_bounds__(1024) void binB_kernel(const int* __restrict__ gcursor,
                                                    const int* __restrict__ bucket_base,
                                                    const int2* __restrict__ staging,
                                                    int2* __restrict__ edges,
                                                    int* __restrict__ row_ptr) {
    __shared__ int s[RB];
    __shared__ int cur[RB];
    int b = blockIdx.x;
    int t = threadIdx.x;
    int cnt = gcursor[b] - b * CAP;
    int sbase = b * CAP;
    int base = bucket_base[b];

    s[t] = 0;
    __syncthreads();
#pragma unroll 4
    for (int i = t; i < cnt; i += RB)
        atomicAdd(&s[((unsigned)staging[sbase + i].x) >> 18], 1);
    __syncthreads();
    int v = s[t];
    __syncthreads();
    // Hillis-Steele inclusive scan (reusing s)
    for (int off = 1; off < RB; off <<= 1) {
        int tv = (t >= off) ? s[t - off] : 0;
        __syncthreads();
        s[t] += tv;
        __syncthreads();
    }
    int excl = s[t] - v;
    int row = b * RB + t;
    if (row < N_NODES) row_ptr[row] = base + excl;
    cur[t] = excl;
    __syncthreads();
#pragma unroll 4
    for (int i = t; i < cnt; i += RB) {
        int2 e = staging[sbase + i];
        int rl = ((unsigned)e.x) >> 18;
        int col = e.x & ((1 << 18) - 1);
        int pos = atomicAdd(&cur[rl], 1);
        edges[base + pos] = make_int2(col, e.y);
    }
}

// ---------------- SpMM + perturbation + mean ----------------
// One wave per row; 4 groups of 16 lanes; each group gathers 4 edges per
// iteration with float4 -> 4 gathers in flight per lane (16 edges/iter/wave).
// mode 0: out = v, x_out = v ; mode 1: out += v, x_out = v ; mode 2: out = (out+v)/3
__global__ __launch_bounds__(256) void spmm_layer_kernel(const float* __restrict__ xu,
                                                         const float* __restrict__ xi,
                                                         float* __restrict__ x_out,
                                                         const int* __restrict__ row_ptr,
                                                         const int2* __restrict__ edges,
                                                         const float* __restrict__ noise_k,
                                                         float* __restrict__ out, int mode) {
    int lane = threadIdx.x & 63;
    int row = blockIdx.x * 4 + (threadIdx.x >> 6);
    if (row >= N_NODES) return;
    int g = lane >> 4;        // edge slot group
    int sub = lane & 15;      // float4 index within the 64-dim row

    int beg = row_ptr[row];
    int end = row_ptr[row + 1];
    int lim = end - 1;

    float4 acc = make_float4(0.f, 0.f, 0.f, 0.f);

    for (int base = beg; base < end; base += 16) {
        int i0 = base + g, i1 = base + 4 + g, i2 = base + 8 + g, i3 = base + 12 + g;
        int2 e0 = edges[min(i0, lim)];
        int2 e1 = edges[min(i1, lim)];
        int2 e2 = edges[min(i2, lim)];
        int2 e3 = edges[min(i3, lim)];
        const float4* q0 = (e0.x < USER_NUM) ? (const float4*)(xu + (long)e0.x * EMB)
                                             : (const float4*)(xi + (long)(e0.x - USER_NUM) * EMB);
        const float4* q1 = (e1.x < USER_NUM) ? (const float4*)(xu + (long)e1.x * EMB)
                                             : (const float4*)(xi + (long)(e1.x - USER_NUM) * EMB);
        const float4* q2 = (e2.x < USER_NUM) ? (const float4*)(xu + (long)e2.x * EMB)
                                             : (const float4*)(xi + (long)(e2.x - USER_NUM) * EMB);
        const float4* q3 = (e3.x < USER_NUM) ? (const float4*)(xu + (long)e3.x * EMB)
                                             : (const float4*)(xi + (long)(e3.x - USER_NUM) * EMB);
        float4 x0 = q0[sub], x1 = q1[sub], x2 = q2[sub], x3 = q3[sub];
        float w0 = (i0 < end) ? __int_as_float(e0.y) : 0.f;
        float w1 = (i1 < end) ? __int_as_float(e1.y) : 0.f;
        float w2 = (i2 < end) ? __int_as_float(e2.y) : 0.f;
        float w3 = (i3 < end) ? __int_as_float(e3.y) : 0.f;
        acc.x += w0 * x0.x; acc.y += w0 * x0.y; acc.z += w0 * x0.z; acc.w += w0 * x0.w;
        acc.x += w1 * x1.x; acc.y += w1 * x1.y; acc.z += w1 * x1.z; acc.w += w1 * x1.w;
        acc.x += w2 * x2.x; acc.y += w2 * x2.y; acc.z += w2 * x2.z; acc.w += w2 * x2.w;
        acc.x += w3 * x3.x; acc.y += w3 * x3.y; acc.z += w3 * x3.z; acc.w += w3 * x3.w;
    }

    // fold the 4 edge-groups
    acc.x += __shfl_xor(acc.x, 16, 64); acc.x += __shfl_xor(acc.x, 32, 64);
    acc.y += __shfl_xor(acc.y, 16, 64); acc.y += __shfl_xor(acc.y, 32, 64);
    acc.z += __shfl_xor(acc.z, 16, 64); acc.z += __shfl_xor(acc.z, 32, 64);
    acc.w += __shfl_xor(acc.w, 16, 64); acc.w += __shfl_xor(acc.w, 32, 64);

    // perturbation: v = acc + sign(acc) * (r/max(||r||,eps)) * EPS
    const float4* nz = (const float4*)(noise_k + (long)row * EMB);
    float4 r4 = nz[sub];
    float ss = r4.x * r4.x + r4.y * r4.y + r4.z * r4.z + r4.w * r4.w;
    ss += __shfl_xor(ss, 1, 64);
    ss += __shfl_xor(ss, 2, 64);
    ss += __shfl_xor(ss, 4, 64);
    ss += __shfl_xor(ss, 8, 64);
    float s = EPS_F / fmaxf(sqrtf(ss), NORM_EPS_F);

    float4 v;
    v.x = acc.x + ((acc.x > 0.f) ? 1.f : ((acc.x < 0.f) ? -1.f : 0.f)) * r4.x * s;
    v.y = acc.y + ((acc.y > 0.f) ? 1.f : ((acc.y < 0.f) ? -1.f : 0.f)) * r4.y * s;
    v.z = acc.z + ((acc.z > 0.f) ? 1.f : ((acc.z < 0.f) ? -1.f : 0.f)) * r4.z * s;
    v.w = acc.w + ((acc.w > 0.f) ? 1.f : ((acc.w < 0.f) ? -1.f : 0.f)) * r4.w * s;

    if (g == 0) {
        float4* po = (float4*)(out + (long)row * EMB);
        if (mode == 0) {
            po[sub] = v;
            ((float4*)(x_out + (long)row * EMB))[sub] = v;
        } else if (mode == 1) {
            float4 o = po[sub];
            o.x += v.x; o.y += v.y; o.z += v.z; o.w += v.w;
            po[sub] = o;
            ((float4*)(x_out + (long)row * EMB))[sub] = v;
        } else {
            float4 o = po[sub];
            o.x = (o.x + v.x) * (1.f / 3.f);
            o.y = (o.y + v.y) * (1.f / 3.f);
            o.z = (o.z + v.z) * (1.f / 3.f);
            o.w = (o.w + v.w) * (1.f / 3.f);
            po[sub] = o;
        }
    }
}

// ---------------- launch ----------------

extern "C" void kernel_launch(void* const* d_in, const int* in_sizes, int n_in,
                              void* d_out, int out_size, void* d_ws, size_t ws_size,
                              hipStream_t stream) {
    const float* user_emb = (const float*)d_in[0];
    const float* item_emb = (const float*)d_in[1];
    const int*   adj_rows = (const int*)d_in[2];
    const int*   adj_cols = (const int*)d_in[3];
    const float* adj_vals = (const float*)d_in[4];
    const float* noise    = (const float*)d_in[5];
    float* out = (float*)d_out;

    char* ws = (char*)d_ws;
    size_t off = 0;
    auto alloc = [&](size_t bytes) {
        char* p = ws + off;
        off += (bytes + 15) & ~size_t(15);
        return p;
    };
    int*   row_ptr     = (int*)alloc((N_NODES + 1) * sizeof(int));
    int*   gcursor     = (int*)alloc(NB * sizeof(int));
    int*   bucket_base = (int*)alloc(NB * sizeof(int));
    int2*  edges       = (int2*)alloc((size_t)NNZ * sizeof(int2));
    float* ego_a       = (float*)alloc((size_t)N_NODES * EMB * sizeof(float));
    float* ego_b       = (float*)alloc((size_t)N_NODES * EMB * sizeof(float));
    // staging (147*36864*8B = 43.4 MB) aliases ego_a+ego_b (76.8 MB contiguous):
    // staging is dead after binB; ego_a first written by layer-0 spmm (after binB).
    int2* staging = (int2*)ego_a;

    // ---- CSR build: 4 kernels total (hist/scans folded into phase B) ----
    init_gcursor<<<1, 256, 0, stream>>>(gcursor);
    binA_kernel<<<BINA_GRID, 1024, 0, stream>>>(adj_rows, adj_cols, adj_vals,
                                                gcursor, staging);
    bscan_kernel<<<1, 256, 0, stream>>>(gcursor, bucket_base, row_ptr);
    binB_kernel<<<NB, 1024, 0, stream>>>(gcursor, bucket_base, staging, edges, row_ptr);

    // ---- 3 layers; layer 0 reads user_emb/item_emb directly ----
    const int LGRID = (N_NODES + 3) / 4;
    const size_t NE = (size_t)N_NODES * EMB;
    spmm_layer_kernel<<<LGRID, 256, 0, stream>>>(user_emb, item_emb, ego_a,
                                                 row_ptr, edges, noise + 0 * NE, out, 0);
    spmm_layer_kernel<<<LGRID, 256, 0, stream>>>(ego_a, ego_a + (size_t)USER_NUM * EMB, ego_b,
                                                 row_ptr, edges, noise + 1 * NE, out, 1);
    spmm_layer_kernel<<<LGRID, 256, 0, stream>>>(ego_b, ego_b + (size_t)USER_NUM * EMB, nullptr,
                                                 row_ptr, edges, noise + 2 * NE, out, 2);
}

// Round 5
// 810.398 us; speedup vs baseline: 1.9423x; 1.2198x over previous
//
#include <hip/hip_runtime.h>

typedef unsigned int uint;

#define USER_NUM   100000
#define ITEM_NUM   50000
#define N_NODES    (USER_NUM + ITEM_NUM)
#define NNZ        4800000
#define EMB        64
#define EPS_F      0.2f
#define NORM_EPS_F 1e-12f

// coarse buckets of 1024 rows
#define RB_SHIFT   10
#define RB         1024
#define NB         ((N_NODES + RB - 1) / RB)     // 147
#define CAP        36864                          // per-bucket staging capacity
#define BINA_CHUNK 16384
#define BINA_GRID  ((NNZ + BINA_CHUNK - 1) / BINA_CHUNK)  // 293

// ---------------- bf16 helpers ----------------
__device__ inline float bflo(uint u) { return __uint_as_float(u << 16); }
__device__ inline float bfhi(uint u) { return __uint_as_float(u & 0xffff0000u); }
__device__ inline uint f2bf(float f) {                 // RNE round to bf16
    uint u = __float_as_uint(f);
    return (u + 0x7fffu + ((u >> 16) & 1u)) >> 16;
}
__device__ inline uint pack2(float a, float b) { return f2bf(a) | (f2bf(b) << 16); }

// ---------------- CSR build ----------------

__global__ void init_gcursor(int* __restrict__ g) {
    int b = blockIdx.x * blockDim.x + threadIdx.x;
    if (b < NB) g[b] = b * CAP;
}

// Phase A: block-private two-pass binning; each block reserves ONE contiguous
// run per bucket (single global atomic) -> line-dense, CU-private writes.
__global__ __launch_bounds__(1024) void binA_kernel(const int* __restrict__ rows,
                                                    const int* __restrict__ cols,
                                                    const float* __restrict__ vals,
                                                    int* __restrict__ gcursor,
                                                    int2* __restrict__ staging) {
    __shared__ int hist[NB];
    __shared__ int cur[NB];
    int t = threadIdx.x;
    int cbeg = blockIdx.x * BINA_CHUNK;
    int cend = min(cbeg + BINA_CHUNK, NNZ);

    if (t < NB) hist[t] = 0;
    __syncthreads();
#pragma unroll 4
    for (int i = cbeg + t; i < cend; i += 1024)
        atomicAdd(&hist[rows[i] >> RB_SHIFT], 1);
    __syncthreads();
    if (t < NB) cur[t] = atomicAdd(&gcursor[t], hist[t]);
    __syncthreads();
#pragma unroll 4
    for (int i = cbeg + t; i < cend; i += 1024) {
        int r = rows[i];
        int pos = atomicAdd(&cur[r >> RB_SHIFT], 1);
        staging[pos] = make_int2(((r & (RB - 1)) << 18) | cols[i], __float_as_int(vals[i]));
    }
}

// exclusive scan of bucket counts -> bucket_base; sentinel row_ptr[N_NODES]
__global__ __launch_bounds__(256) void bscan_kernel(const int* __restrict__ gcursor,
                                                    int* __restrict__ bucket_base,
                                                    int* __restrict__ row_ptr) {
    __shared__ int s[256];
    int t = threadIdx.x;
    int c = (t < NB) ? (gcursor[t] - t * CAP) : 0;
    s[t] = c;
    __syncthreads();
    for (int off = 1; off < 256; off <<= 1) {
        int tv = (t >= off) ? s[t - off] : 0;
        __syncthreads();
        s[t] += tv;
        __syncthreads();
    }
    if (t < NB) bucket_base[t] = s[t] - c;
    if (t == 0) row_ptr[N_NODES] = NNZ;
}

// Phase B: one block per bucket: LDS hist + scan -> row_ptr, then scatter into
// the bucket's contiguous CSR segment (single CU -> dense writes).
__global__ __launch_bounds__(1024) void binB_kernel(const int* __restrict__ gcursor,
                                                    const int* __restrict__ bucket_base,
                                                    const int2* __restrict__ staging,
                                                    int2* __restrict__ edges,
                                                    int* __restrict__ row_ptr) {
    __shared__ int s[RB];
    __shared__ int cur[RB];
    int b = blockIdx.x;
    int t = threadIdx.x;
    int cnt = gcursor[b] - b * CAP;
    int sbase = b * CAP;
    int base = bucket_base[b];

    s[t] = 0;
    __syncthreads();
#pragma unroll 4
    for (int i = t; i < cnt; i += RB)
        atomicAdd(&s[((unsigned)staging[sbase + i].x) >> 18], 1);
    __syncthreads();
    int v = s[t];
    __syncthreads();
    for (int off = 1; off < RB; off <<= 1) {
        int tv = (t >= off) ? s[t - off] : 0;
        __syncthreads();
        s[t] += tv;
        __syncthreads();
    }
    int excl = s[t] - v;
    int row = b * RB + t;
    if (row < N_NODES) row_ptr[row] = base + excl;
    cur[t] = excl;
    __syncthreads();
#pragma unroll 4
    for (int i = t; i < cnt; i += RB) {
        int2 e = staging[sbase + i];
        int rl = ((unsigned)e.x) >> 18;
        int col = e.x & ((1 << 18) - 1);
        int pos = atomicAdd(&cur[rl], 1);
        edges[base + pos] = make_int2(col, e.y);
    }
}

// concat(user,item) fp32 -> packed bf16 (2 per uint), fused with concat
__global__ void convert_kernel(const float4* __restrict__ u, const float4* __restrict__ it,
                               uint2* __restrict__ xh) {
    const int NU4 = USER_NUM * EMB / 4;
    const int NT4 = N_NODES * EMB / 4;
    int i = blockIdx.x * blockDim.x + threadIdx.x;
    int stride = gridDim.x * blockDim.x;
    for (; i < NT4; i += stride) {
        float4 f = (i < NU4) ? u[i] : it[i - NU4];
        xh[i] = make_uint2(pack2(f.x, f.y), pack2(f.z, f.w));
    }
}

// ---------------- SpMM (bf16 gather) + perturbation + mean ----------------
// One wave per row; 8 groups of 8 lanes. Each lane loads 16B = 8 bf16 dims of
// one neighbor row; 2 edges in flight per lane (16 edges/iter/wave).
// mode 0: out = v ; mode 1: out += v ; mode 2: out = (out+v)/3
// x_out (bf16) written in modes 0/1.
__global__ __launch_bounds__(256) void spmm_layer_kernel(const uint* __restrict__ x,
                                                         uint* __restrict__ x_out,
                                                         const int* __restrict__ row_ptr,
                                                         const int2* __restrict__ edges,
                                                         const float* __restrict__ noise_k,
                                                         float* __restrict__ out, int mode) {
    int lane = threadIdx.x & 63;
    int row = blockIdx.x * 4 + (threadIdx.x >> 6);
    if (row >= N_NODES) return;
    int g = lane >> 3;        // edge group 0..7
    int sub = lane & 7;       // dim slice: dims [sub*8, sub*8+8)

    int beg = row_ptr[row];
    int end = row_ptr[row + 1];
    int lim = end - 1;

    float a0 = 0.f, a1 = 0.f, a2 = 0.f, a3 = 0.f;
    float a4 = 0.f, a5 = 0.f, a6 = 0.f, a7 = 0.f;

    for (int base = beg; base < end; base += 16) {
        int i0 = base + g, i1 = base + 8 + g;
        int2 e0 = edges[min(i0, lim)];
        int2 e1 = edges[min(i1, lim)];
        const uint4* q0 = (const uint4*)(x + (long)e0.x * (EMB / 2));
        const uint4* q1 = (const uint4*)(x + (long)e1.x * (EMB / 2));
        uint4 h0 = q0[sub];                       // 8 bf16 dims, 16B coalesced
        uint4 h1 = q1[sub];
        float w0 = (i0 < end) ? __int_as_float(e0.y) : 0.f;
        float w1 = (i1 < end) ? __int_as_float(e1.y) : 0.f;
        a0 += w0 * bflo(h0.x); a1 += w0 * bfhi(h0.x);
        a2 += w0 * bflo(h0.y); a3 += w0 * bfhi(h0.y);
        a4 += w0 * bflo(h0.z); a5 += w0 * bfhi(h0.z);
        a6 += w0 * bflo(h0.w); a7 += w0 * bfhi(h0.w);
        a0 += w1 * bflo(h1.x); a1 += w1 * bfhi(h1.x);
        a2 += w1 * bflo(h1.y); a3 += w1 * bfhi(h1.y);
        a4 += w1 * bflo(h1.z); a5 += w1 * bfhi(h1.z);
        a6 += w1 * bflo(h1.w); a7 += w1 * bfhi(h1.w);
    }

    // fold the 8 edge-groups (bits 3,4,5 of lane)
#pragma unroll
    for (int off = 8; off <= 32; off <<= 1) {
        a0 += __shfl_xor(a0, off, 64); a1 += __shfl_xor(a1, off, 64);
        a2 += __shfl_xor(a2, off, 64); a3 += __shfl_xor(a3, off, 64);
        a4 += __shfl_xor(a4, off, 64); a5 += __shfl_xor(a5, off, 64);
        a6 += __shfl_xor(a6, off, 64); a7 += __shfl_xor(a7, off, 64);
    }

    // perturbation: v = acc + sign(acc) * (r/max(||r||,eps)) * EPS  (fp32 noise)
    const float4* nz = (const float4*)(noise_k + (long)row * EMB);
    float4 n0 = nz[sub * 2];
    float4 n1 = nz[sub * 2 + 1];
    float ss = n0.x * n0.x + n0.y * n0.y + n0.z * n0.z + n0.w * n0.w
             + n1.x * n1.x + n1.y * n1.y + n1.z * n1.z + n1.w * n1.w;
    ss += __shfl_xor(ss, 1, 64);
    ss += __shfl_xor(ss, 2, 64);
    ss += __shfl_xor(ss, 4, 64);
    float s = EPS_F / fmaxf(sqrtf(ss), NORM_EPS_F);

    float v0 = a0 + ((a0 > 0.f) ? 1.f : ((a0 < 0.f) ? -1.f : 0.f)) * n0.x * s;
    float v1 = a1 + ((a1 > 0.f) ? 1.f : ((a1 < 0.f) ? -1.f : 0.f)) * n0.y * s;
    float v2 = a2 + ((a2 > 0.f) ? 1.f : ((a2 < 0.f) ? -1.f : 0.f)) * n0.z * s;
    float v3 = a3 + ((a3 > 0.f) ? 1.f : ((a3 < 0.f) ? -1.f : 0.f)) * n0.w * s;
    float v4 = a4 + ((a4 > 0.f) ? 1.f : ((a4 < 0.f) ? -1.f : 0.f)) * n1.x * s;
    float v5 = a5 + ((a5 > 0.f) ? 1.f : ((a5 < 0.f) ? -1.f : 0.f)) * n1.y * s;
    float v6 = a6 + ((a6 > 0.f) ? 1.f : ((a6 < 0.f) ? -1.f : 0.f)) * n1.z * s;
    float v7 = a7 + ((a7 > 0.f) ? 1.f : ((a7 < 0.f) ? -1.f : 0.f)) * n1.w * s;

    if (g == 0) {
        float4* po = (float4*)(out + (long)row * EMB);
        float4 f01 = make_float4(v0, v1, v2, v3);
        float4 f23 = make_float4(v4, v5, v6, v7);
        if (mode == 0) {
            po[sub * 2] = f01;
            po[sub * 2 + 1] = f23;
        } else if (mode == 1) {
            float4 o0 = po[sub * 2], o1 = po[sub * 2 + 1];
            o0.x += v0; o0.y += v1; o0.z += v2; o0.w += v3;
            o1.x += v4; o1.y += v5; o1.z += v6; o1.w += v7;
            po[sub * 2] = o0;
            po[sub * 2 + 1] = o1;
        } else {
            float4 o0 = po[sub * 2], o1 = po[sub * 2 + 1];
            o0.x = (o0.x + v0) * (1.f / 3.f); o0.y = (o0.y + v1) * (1.f / 3.f);
            o0.z = (o0.z + v2) * (1.f / 3.f); o0.w = (o0.w + v3) * (1.f / 3.f);
            o1.x = (o1.x + v4) * (1.f / 3.f); o1.y = (o1.y + v5) * (1.f / 3.f);
            o1.z = (o1.z + v6) * (1.f / 3.f); o1.w = (o1.w + v7) * (1.f / 3.f);
            po[sub * 2] = o0;
            po[sub * 2 + 1] = o1;
        }
        if (mode != 2) {
            uint4* ph = (uint4*)(x_out + (long)row * (EMB / 2));
            ph[sub] = make_uint4(pack2(v0, v1), pack2(v2, v3),
                                 pack2(v4, v5), pack2(v6, v7));
        }
    }
}

// ---------------- launch ----------------

extern "C" void kernel_launch(void* const* d_in, const int* in_sizes, int n_in,
                              void* d_out, int out_size, void* d_ws, size_t ws_size,
                              hipStream_t stream) {
    const float* user_emb = (const float*)d_in[0];
    const float* item_emb = (const float*)d_in[1];
    const int*   adj_rows = (const int*)d_in[2];
    const int*   adj_cols = (const int*)d_in[3];
    const float* adj_vals = (const float*)d_in[4];
    const float* noise    = (const float*)d_in[5];
    float* out = (float*)d_out;

    char* ws = (char*)d_ws;
    size_t off = 0;
    auto alloc = [&](size_t bytes) {
        char* p = ws + off;
        off += (bytes + 15) & ~size_t(15);
        return p;
    };
    int*   row_ptr     = (int*)alloc((N_NODES + 1) * sizeof(int));
    int*   gcursor     = (int*)alloc(NB * sizeof(int));
    int*   bucket_base = (int*)alloc(NB * sizeof(int));
    int2*  edges       = (int2*)alloc((size_t)NNZ * sizeof(int2));
    int2*  staging     = (int2*)alloc((size_t)NB * CAP * sizeof(int2));  // 43.4 MB
    // bf16 x buffers alias staging (staging dead after binB; xh_a written by
    // convert_kernel which runs after binB; xh_b first written by layer 0).
    uint* xh_a = (uint*)staging;                                   // 19.2 MB
    uint* xh_b = (uint*)((char*)staging + (size_t)N_NODES * EMB * 2);

    // ---- CSR build ----
    init_gcursor<<<1, 256, 0, stream>>>(gcursor);
    binA_kernel<<<BINA_GRID, 1024, 0, stream>>>(adj_rows, adj_cols, adj_vals,
                                                gcursor, staging);
    bscan_kernel<<<1, 256, 0, stream>>>(gcursor, bucket_base, row_ptr);
    binB_kernel<<<NB, 1024, 0, stream>>>(gcursor, bucket_base, staging, edges, row_ptr);

    // ---- fp32 -> bf16 convert (fused concat) ----
    convert_kernel<<<2048, 256, 0, stream>>>((const float4*)user_emb,
                                             (const float4*)item_emb, (uint2*)xh_a);

    // ---- 3 layers ----
    const int LGRID = (N_NODES + 3) / 4;
    const size_t NE = (size_t)N_NODES * EMB;
    spmm_layer_kernel<<<LGRID, 256, 0, stream>>>(xh_a, xh_b, row_ptr, edges,
                                                 noise + 0 * NE, out, 0);
    spmm_layer_kernel<<<LGRID, 256, 0, stream>>>(xh_b, xh_a, row_ptr, edges,
                                                 noise + 1 * NE, out, 1);
    spmm_layer_kernel<<<LGRID, 256, 0, stream>>>(xh_a, nullptr, row_ptr, edges,
                                                 noise + 2 * NE, out, 2);
}